// Round 2
// baseline (3493.325 us; speedup 1.0000x reference)
//
#include <hip/hip_runtime.h>

typedef unsigned short u16;
typedef unsigned int u32;
typedef __attribute__((ext_vector_type(8))) short short8;   // 8 bf16 = 4 VGPR
typedef __attribute__((ext_vector_type(4))) float f32x4;    // MFMA acc

#define NTOK 4096
#define CDIM 2048
#define EDIM 8
#define IDIM 5632

// round-half-up fp32 -> bf16 (bias only on exact .5 ties; ~RNE accuracy, 1 VALU)
__device__ inline u32 f2bf_u(float f) {
    return (__float_as_uint(f) + 0x8000u) >> 16;
}
__device__ inline u16 f2bf(float f) { return (u16)f2bf_u(f); }

// pack two floats' bf16 into one u32: low = x, high = y  (3 VALU total)
__device__ inline u32 pk2(float x, float y) {
    u32 ux = __float_as_uint(x) + 0x8000u;
    u32 uy = __float_as_uint(y) + 0x8000u;
    return __builtin_amdgcn_perm(uy, ux, 0x07060302u);  // [y3 y2 x3 x2]
}
__device__ inline uint4 pack8(float4 a, float4 b) {
    uint4 r;
    r.x = pk2(a.x, a.y); r.y = pk2(a.z, a.w);
    r.z = pk2(b.x, b.y); r.w = pk2(b.z, b.w);
    return r;
}

// async 16B global->LDS DMA. LDS dest: wave-uniform base + lane*16.
typedef const __attribute__((address_space(1))) u32* gas_p;
typedef __attribute__((address_space(3))) u32* las_p;
__device__ inline void gld16(const void* g, void* l) {
    __builtin_amdgcn_global_load_lds((gas_p)g, (las_p)l, 16, 0, 0);
}

// ---------------- router: 1 wave per token ----------------
__global__ __launch_bounds__(256) void router_kernel(
    const float* __restrict__ x, const float* __restrict__ gw,
    int* __restrict__ cnt, int* __restrict__ tk_e,
    float* __restrict__ tk_p, int* __restrict__ tk_pos) {
    int n = blockIdx.x * 4 + (threadIdx.x >> 6);
    int lane = threadIdx.x & 63;
    float acc[EDIM];
#pragma unroll
    for (int e = 0; e < EDIM; ++e) acc[e] = 0.f;
    const float4* x4 = (const float4*)(x + (size_t)n * CDIM);
    const float4* g4 = (const float4*)gw;
#pragma unroll
    for (int i = 0; i < 8; ++i) {
        int idx = i * 64 + lane;           // 512 float4 per row
        float4 xv = x4[idx];
#pragma unroll
        for (int e = 0; e < EDIM; ++e) {
            float4 gv = g4[e * 512 + idx];
            acc[e] += xv.x * gv.x + xv.y * gv.y + xv.z * gv.z + xv.w * gv.w;
        }
    }
#pragma unroll
    for (int off = 32; off; off >>= 1)
#pragma unroll
        for (int e = 0; e < EDIM; ++e) acc[e] += __shfl_xor(acc[e], off, 64);
    if (lane == 0) {
        int i1 = 0; float v1 = acc[0];
#pragma unroll
        for (int e = 1; e < EDIM; ++e) if (acc[e] > v1) { v1 = acc[e]; i1 = e; }
        int i2 = -1; float v2 = -3.0e38f;
#pragma unroll
        for (int e = 0; e < EDIM; ++e) if (e != i1 && acc[e] > v2) { v2 = acc[e]; i2 = e; }
        float p1 = 1.f / (1.f + __expf(v2 - v1));  // v2 <= v1, stable
        float p2 = 1.f - p1;
        tk_e[n * 2] = i1;  tk_e[n * 2 + 1] = i2;
        tk_p[n * 2] = p1;  tk_p[n * 2 + 1] = p2;
        tk_pos[n * 2]     = atomicAdd(&cnt[i1], 1);
        tk_pos[n * 2 + 1] = atomicAdd(&cnt[i2], 1);
    }
}

// ---------------- exclusive scan of 8 counts ----------------
__global__ void scan_kernel(const int* __restrict__ cnt, int* __restrict__ off) {
    if (threadIdx.x == 0) {
        int s = 0;
        for (int e = 0; e < EDIM; ++e) { off[e] = s; s += cnt[e]; }
    }
}

// ---------------- gather x rows -> contiguous bf16 A, build slot maps ----------------
__global__ __launch_bounds__(256) void gather_kernel(
    const float* __restrict__ x, const int* __restrict__ tk_e,
    const float* __restrict__ tk_p, const int* __restrict__ tk_pos,
    const int* __restrict__ off, int* __restrict__ slot_tok,
    float* __restrict__ slot_prob, u16* __restrict__ Axg) {
    int b = blockIdx.x;            // 0..8191
    int n = b >> 1, k = b & 1;
    int e = tk_e[n * 2 + k];
    int slot = off[e] + tk_pos[n * 2 + k];
    int t = threadIdx.x;
    if (t == 0) { slot_tok[slot] = n; slot_prob[slot] = tk_p[n * 2 + k]; }
    const float4* src = (const float4*)(x + (size_t)n * CDIM);
    float4 a = src[t * 2], c = src[t * 2 + 1];
    ((uint4*)(Axg + (size_t)slot * CDIM))[t] = pack8(a, c);
}

// ---------------- weight fp32 -> bf16 conversion (grid-stride, 8 elems/iter) ----------------
__global__ __launch_bounds__(256) void cvt_bf16_kernel(
    const float* __restrict__ src, u16* __restrict__ dst, long long n8) {
    long long stride = (long long)gridDim.x * 256;
    for (long long i = (long long)blockIdx.x * 256 + threadIdx.x; i < n8; i += stride) {
        const float4* s4 = (const float4*)src + i * 2;
        float4 a = s4[0], b = s4[1];
        ((uint4*)dst)[i] = pack8(a, b);
    }
}

// ==================== bf16-weight fast path ====================
// GEMM1: tile M=128 x N=64, BK=32, 4 waves (2x2), all staging via global_load_lds.
// m97 2-barrier structure: barrier; issue DMA; barrier(vmcnt drain); ds_read+MFMA.
__global__ __launch_bounds__(256, 2) void gemm1_bf16(
    const u16* __restrict__ Axg, const u16* __restrict__ fc1b,
    const u16* __restrict__ fc2b, const int* __restrict__ cnt,
    const int* __restrict__ offs, u16* __restrict__ h) {
    const int e = blockIdx.z;
    const int ce = cnt[e];
    const int rowbase = blockIdx.x * 128;
    if (rowbase >= ce) return;
    const int oe = offs[e];
    const int colbase = blockIdx.y * 64;

    __shared__ alignas(16) u16 As[128 * 32];
    __shared__ alignas(16) u16 B1s[64 * 32];
    __shared__ alignas(16) u16 B2s[64 * 32];

    const int t = threadIdx.x;
    const int lane = t & 63;
    const int w = t >> 6;
    const int wm = w >> 1, wn = w & 1;
    const int lr = lane & 15, lq = lane >> 4;

    // A: 512 16B chunks, 2/thread. chunk c -> row c>>2, sub (c&3)*8 elems
    const int c0 = t, c1 = 256 + t;
    int ar0 = rowbase + (c0 >> 2); if (ar0 > ce - 1) ar0 = ce - 1;
    int ar1 = rowbase + (c1 >> 2); if (ar1 > ce - 1) ar1 = ce - 1;
    const u16* pa0 = Axg + (size_t)(oe + ar0) * CDIM + (c0 & 3) * 8;
    const u16* pa1 = Axg + (size_t)(oe + ar1) * CDIM + (c1 & 3) * 8;
    // B: 256 chunks each, 1/thread. row t>>2 (64 rows), sub (t&3)*8
    const int brow = t >> 2, bsub = t & 3;
    const u16* pb1 = fc1b + ((size_t)e * IDIM + colbase + brow) * CDIM + bsub * 8;
    const u16* pb2 = fc2b + ((size_t)e * IDIM + colbase + brow) * CDIM + bsub * 8;

    // wave-uniform LDS DMA bases (chunk index = wave_chunk_base + lane)
    u16* As_d0 = As + (size_t)w * 512;          // chunks w*64 .. w*64+63
    u16* As_d1 = As + 2048 + (size_t)w * 512;   // chunks 256+w*64 ..
    u16* B1_d  = B1s + (size_t)w * 512;
    u16* B2_d  = B2s + (size_t)w * 512;

    f32x4 acc1[4][2], acc2[4][2];
#pragma unroll
    for (int mi = 0; mi < 4; ++mi)
#pragma unroll
        for (int ni = 0; ni < 2; ++ni) {
            acc1[mi][ni] = (f32x4){0.f, 0.f, 0.f, 0.f};
            acc2[mi][ni] = (f32x4){0.f, 0.f, 0.f, 0.f};
        }

    for (int k0 = 0; k0 < CDIM; k0 += 32) {
        __syncthreads();                 // prev iter's ds_reads done before overwrite
        gld16(pa0 + k0, As_d0);
        gld16(pa1 + k0, As_d1);
        gld16(pb1 + k0, B1_d);
        gld16(pb2 + k0, B2_d);
        __syncthreads();                 // implicit vmcnt(0) drain -> LDS ready

        short8 af[4], b1f[2], b2f[2];
#pragma unroll
        for (int mi = 0; mi < 4; ++mi)
            af[mi] = *(const short8*)&As[(wm * 64 + mi * 16 + lr) * 32 + lq * 8];
#pragma unroll
        for (int ni = 0; ni < 2; ++ni) {
            b1f[ni] = *(const short8*)&B1s[(wn * 32 + ni * 16 + lr) * 32 + lq * 8];
            b2f[ni] = *(const short8*)&B2s[(wn * 32 + ni * 16 + lr) * 32 + lq * 8];
        }
#pragma unroll
        for (int mi = 0; mi < 4; ++mi)
#pragma unroll
            for (int ni = 0; ni < 2; ++ni) {
                acc1[mi][ni] = __builtin_amdgcn_mfma_f32_16x16x32_bf16(af[mi], b1f[ni], acc1[mi][ni], 0, 0, 0);
                acc2[mi][ni] = __builtin_amdgcn_mfma_f32_16x16x32_bf16(af[mi], b2f[ni], acc2[mi][ni], 0, 0, 0);
            }
    }

    // epilogue: h = silu(a1) * a2  (C/D layout: col=lane&15, row=(lane>>4)*4+reg)
#pragma unroll
    for (int mi = 0; mi < 4; ++mi) {
        int r0 = rowbase + wm * 64 + mi * 16 + lq * 4;
#pragma unroll
        for (int reg = 0; reg < 4; ++reg) {
            int r = r0 + reg;
            if (r < ce) {
                size_t slot = (size_t)(oe + r);
#pragma unroll
                for (int ni = 0; ni < 2; ++ni) {
                    int col = colbase + wn * 32 + ni * 16 + lr;
                    float a1v = acc1[mi][ni][reg];
                    float a2v = acc2[mi][ni][reg];
                    float hv = (a1v / (1.f + __expf(-a1v))) * a2v;
                    h[slot * IDIM + col] = f2bf(hv);
                }
            }
        }
    }
}

// GEMM2: tile M=128 x N=128 (m97 config), BK=32, 4 waves each 64x64.
__global__ __launch_bounds__(256, 2) void gemm2_bf16(
    const u16* __restrict__ h, const u16* __restrict__ projb,
    const int* __restrict__ cnt, const int* __restrict__ offs,
    const int* __restrict__ slot_tok, const float* __restrict__ slot_prob,
    float* __restrict__ out) {
    const int e = blockIdx.z;
    const int ce = cnt[e];
    const int rowbase = blockIdx.x * 128;
    if (rowbase >= ce) return;
    const int oe = offs[e];
    const int colbase = blockIdx.y * 128;

    __shared__ alignas(16) u16 As[128 * 32];
    __shared__ alignas(16) u16 Bs[128 * 32];

    const int t = threadIdx.x;
    const int lane = t & 63;
    const int w = t >> 6;
    const int wm = w >> 1, wn = w & 1;
    const int lr = lane & 15, lq = lane >> 4;

    const int c0 = t, c1 = 256 + t;
    int ar0 = rowbase + (c0 >> 2); if (ar0 > ce - 1) ar0 = ce - 1;
    int ar1 = rowbase + (c1 >> 2); if (ar1 > ce - 1) ar1 = ce - 1;
    const u16* pa0 = h + (size_t)(oe + ar0) * IDIM + (c0 & 3) * 8;
    const u16* pa1 = h + (size_t)(oe + ar1) * IDIM + (c1 & 3) * 8;
    // B: 128 rows x 32 cols = 512 chunks, 2/thread
    const u16* pb0 = projb + ((size_t)e * CDIM + colbase + (c0 >> 2)) * IDIM + (c0 & 3) * 8;
    const u16* pb1 = projb + ((size_t)e * CDIM + colbase + (c1 >> 2)) * IDIM + (c1 & 3) * 8;

    u16* As_d0 = As + (size_t)w * 512;
    u16* As_d1 = As + 2048 + (size_t)w * 512;
    u16* Bs_d0 = Bs + (size_t)w * 512;
    u16* Bs_d1 = Bs + 2048 + (size_t)w * 512;

    f32x4 acc[4][4];
#pragma unroll
    for (int mi = 0; mi < 4; ++mi)
#pragma unroll
        for (int ni = 0; ni < 4; ++ni) acc[mi][ni] = (f32x4){0.f, 0.f, 0.f, 0.f};

    for (int k0 = 0; k0 < IDIM; k0 += 32) {
        __syncthreads();
        gld16(pa0 + k0, As_d0);
        gld16(pa1 + k0, As_d1);
        gld16(pb0 + k0, Bs_d0);
        gld16(pb1 + k0, Bs_d1);
        __syncthreads();

        short8 af[4], bf[4];
#pragma unroll
        for (int mi = 0; mi < 4; ++mi)
            af[mi] = *(const short8*)&As[(wm * 64 + mi * 16 + lr) * 32 + lq * 8];
#pragma unroll
        for (int ni = 0; ni < 4; ++ni)
            bf[ni] = *(const short8*)&Bs[(wn * 64 + ni * 16 + lr) * 32 + lq * 8];
#pragma unroll
        for (int mi = 0; mi < 4; ++mi)
#pragma unroll
            for (int ni = 0; ni < 4; ++ni)
                acc[mi][ni] = __builtin_amdgcn_mfma_f32_16x16x32_bf16(af[mi], bf[ni], acc[mi][ni], 0, 0, 0);
    }

#pragma unroll
    for (int mi = 0; mi < 4; ++mi) {
        int r0 = rowbase + wm * 64 + mi * 16 + lq * 4;
#pragma unroll
        for (int reg = 0; reg < 4; ++reg) {
            int r = r0 + reg;
            if (r < ce) {
                int slot = oe + r;
                int tok = slot_tok[slot];
                float p = slot_prob[slot];
#pragma unroll
                for (int ni = 0; ni < 4; ++ni) {
                    int col = colbase + wn * 64 + ni * 16 + lr;
                    atomicAdd(out + (size_t)tok * CDIM + col, p * acc[mi][ni][reg]);
                }
            }
        }
    }
}

// ==================== fp32-weight fallback (previous verified kernels) ====================
__global__ __launch_bounds__(256, 2) void gemm1_kernel(
    const u16* __restrict__ Axg, const float* __restrict__ fc1,
    const float* __restrict__ fc2, const int* __restrict__ cnt,
    const int* __restrict__ offs, u16* __restrict__ h) {
    const int e = blockIdx.z;
    const int ce = cnt[e];
    const int rowbase = blockIdx.x * 128;
    if (rowbase >= ce) return;
    const int oe = offs[e];
    const int colbase = blockIdx.y * 64;

    __shared__ alignas(16) u16 As[128 * 32];
    __shared__ alignas(16) u16 B1s[64 * 32];
    __shared__ alignas(16) u16 B2s[64 * 32];

    const int t = threadIdx.x;
    const int lane = t & 63;
    const int w = t >> 6;
    const int wm = w >> 1, wn = w & 1;
    const int lr = lane & 15, lq = lane >> 4;

    const int c0 = t, c1 = 256 + t;
    int ar0 = rowbase + (c0 >> 2); if (ar0 > ce - 1) ar0 = ce - 1;
    int ar1 = rowbase + (c1 >> 2); if (ar1 > ce - 1) ar1 = ce - 1;
    const u16* pa0 = Axg + (size_t)(oe + ar0) * CDIM + (c0 & 3) * 8;
    const u16* pa1 = Axg + (size_t)(oe + ar1) * CDIM + (c1 & 3) * 8;
    const int brow = t >> 2, bsub = t & 3;
    const float* pb1 = fc1 + ((size_t)e * IDIM + colbase + brow) * CDIM + bsub * 8;
    const float* pb2 = fc2 + ((size_t)e * IDIM + colbase + brow) * CDIM + bsub * 8;

    f32x4 acc1[4][2], acc2[4][2];
#pragma unroll
    for (int mi = 0; mi < 4; ++mi)
#pragma unroll
        for (int ni = 0; ni < 2; ++ni) {
            acc1[mi][ni] = (f32x4){0.f, 0.f, 0.f, 0.f};
            acc2[mi][ni] = (f32x4){0.f, 0.f, 0.f, 0.f};
        }

    for (int k0 = 0; k0 < CDIM; k0 += 32) {
        uint4 av0 = *(const uint4*)(pa0 + k0);
        uint4 av1 = *(const uint4*)(pa1 + k0);
        float4 b1a = *(const float4*)(pb1 + k0);
        float4 b1b = *(const float4*)(pb1 + k0 + 4);
        float4 b2a = *(const float4*)(pb2 + k0);
        float4 b2b = *(const float4*)(pb2 + k0 + 4);
        __syncthreads();
        ((uint4*)As)[c0] = av0;
        ((uint4*)As)[c1] = av1;
        ((uint4*)B1s)[t] = pack8(b1a, b1b);
        ((uint4*)B2s)[t] = pack8(b2a, b2b);
        __syncthreads();

        short8 af[4], b1f[2], b2f[2];
#pragma unroll
        for (int mi = 0; mi < 4; ++mi)
            af[mi] = *(const short8*)&As[(wm * 64 + mi * 16 + lr) * 32 + lq * 8];
#pragma unroll
        for (int ni = 0; ni < 2; ++ni) {
            b1f[ni] = *(const short8*)&B1s[(wn * 32 + ni * 16 + lr) * 32 + lq * 8];
            b2f[ni] = *(const short8*)&B2s[(wn * 32 + ni * 16 + lr) * 32 + lq * 8];
        }
#pragma unroll
        for (int mi = 0; mi < 4; ++mi)
#pragma unroll
            for (int ni = 0; ni < 2; ++ni) {
                acc1[mi][ni] = __builtin_amdgcn_mfma_f32_16x16x32_bf16(af[mi], b1f[ni], acc1[mi][ni], 0, 0, 0);
                acc2[mi][ni] = __builtin_amdgcn_mfma_f32_16x16x32_bf16(af[mi], b2f[ni], acc2[mi][ni], 0, 0, 0);
            }
    }

#pragma unroll
    for (int mi = 0; mi < 4; ++mi) {
        int r0 = rowbase + wm * 64 + mi * 16 + lq * 4;
#pragma unroll
        for (int reg = 0; reg < 4; ++reg) {
            int r = r0 + reg;
            if (r < ce) {
                size_t slot = (size_t)(oe + r);
#pragma unroll
                for (int ni = 0; ni < 2; ++ni) {
                    int col = colbase + wn * 32 + ni * 16 + lr;
                    float a1v = acc1[mi][ni][reg];
                    float a2v = acc2[mi][ni][reg];
                    float hv = (a1v / (1.f + __expf(-a1v))) * a2v;
                    h[slot * IDIM + col] = f2bf(hv);
                }
            }
        }
    }
}

__global__ __launch_bounds__(256, 2) void gemm2_kernel(
    const u16* __restrict__ h, const float* __restrict__ proj,
    const int* __restrict__ cnt, const int* __restrict__ offs,
    const int* __restrict__ slot_tok, const float* __restrict__ slot_prob,
    float* __restrict__ out) {
    const int e = blockIdx.z;
    const int ce = cnt[e];
    const int rowbase = blockIdx.x * 128;
    if (rowbase >= ce) return;
    const int oe = offs[e];
    const int colbase = blockIdx.y * 64;

    __shared__ alignas(16) u16 As[128 * 32];
    __shared__ alignas(16) u16 Bs[64 * 32];

    const int t = threadIdx.x;
    const int lane = t & 63;
    const int w = t >> 6;
    const int wm = w >> 1, wn = w & 1;
    const int lr = lane & 15, lq = lane >> 4;

    const int c0 = t, c1 = 256 + t;
    int ar0 = rowbase + (c0 >> 2); if (ar0 > ce - 1) ar0 = ce - 1;
    int ar1 = rowbase + (c1 >> 2); if (ar1 > ce - 1) ar1 = ce - 1;
    const u16* pa0 = h + (size_t)(oe + ar0) * IDIM + (c0 & 3) * 8;
    const u16* pa1 = h + (size_t)(oe + ar1) * IDIM + (c1 & 3) * 8;
    const int brow = t >> 2, bsub = t & 3;
    const float* pb = proj + ((size_t)e * CDIM + colbase + brow) * IDIM + bsub * 8;

    f32x4 acc[4][2];
#pragma unroll
    for (int mi = 0; mi < 4; ++mi)
#pragma unroll
        for (int ni = 0; ni < 2; ++ni) acc[mi][ni] = (f32x4){0.f, 0.f, 0.f, 0.f};

    for (int k0 = 0; k0 < IDIM; k0 += 32) {
        uint4 av0 = *(const uint4*)(pa0 + k0);
        uint4 av1 = *(const uint4*)(pa1 + k0);
        float4 ba = *(const float4*)(pb + k0);
        float4 bb = *(const float4*)(pb + k0 + 4);
        __syncthreads();
        ((uint4*)As)[c0] = av0;
        ((uint4*)As)[c1] = av1;
        ((uint4*)Bs)[t] = pack8(ba, bb);
        __syncthreads();

        short8 af[4], bf[2];
#pragma unroll
        for (int mi = 0; mi < 4; ++mi)
            af[mi] = *(const short8*)&As[(wm * 64 + mi * 16 + lr) * 32 + lq * 8];
#pragma unroll
        for (int ni = 0; ni < 2; ++ni)
            bf[ni] = *(const short8*)&Bs[(wn * 32 + ni * 16 + lr) * 32 + lq * 8];
#pragma unroll
        for (int mi = 0; mi < 4; ++mi)
#pragma unroll
            for (int ni = 0; ni < 2; ++ni)
                acc[mi][ni] = __builtin_amdgcn_mfma_f32_16x16x32_bf16(af[mi], bf[ni], acc[mi][ni], 0, 0, 0);
    }

#pragma unroll
    for (int mi = 0; mi < 4; ++mi) {
        int r0 = rowbase + wm * 64 + mi * 16 + lq * 4;
#pragma unroll
        for (int reg = 0; reg < 4; ++reg) {
            int r = r0 + reg;
            if (r < ce) {
                int slot = oe + r;
                int tok = slot_tok[slot];
                float p = slot_prob[slot];
#pragma unroll
                for (int ni = 0; ni < 2; ++ni) {
                    int col = colbase + wn * 32 + ni * 16 + lr;
                    atomicAdd(out + (size_t)tok * CDIM + col, p * acc[mi][ni][reg]);
                }
            }
        }
    }
}

extern "C" void kernel_launch(void* const* d_in, const int* in_sizes, int n_in,
                              void* d_out, int out_size, void* d_ws, size_t ws_size,
                              hipStream_t stream) {
    const float* x      = (const float*)d_in[0];
    const float* gate_w = (const float*)d_in[1];
    const float* fc1_w  = (const float*)d_in[2];
    const float* fc2_w  = (const float*)d_in[3];
    const float* proj_w = (const float*)d_in[4];
    float* out = (float*)d_out;

    char* ws = (char*)d_ws;
    int*   cnt       = (int*)(ws + 0);
    int*   off       = (int*)(ws + 64);
    int*   tk_e      = (int*)(ws + 128);                 // 4096*2 ints = 32KB
    float* tk_p      = (float*)(ws + 128 + 32768);
    int*   tk_pos    = (int*)(ws + 128 + 65536);
    int*   slot_tok  = (int*)(ws + 128 + 98304);         // 8192 ints
    float* slot_prob = (float*)(ws + 128 + 131072);
    u16*   Axg       = (u16*)(ws + 262144);                            // 8192*2048 bf16 = 33.5MB
    u16*   hbuf      = (u16*)(ws + 262144 + (size_t)8192 * 2048 * 2);  // 8192*5632 bf16 = 92.3MB

    const size_t WELEM = (size_t)EDIM * IDIM * CDIM;                   // 92,274,688 elems/tensor
    const size_t base_end = 262144 + (size_t)8192 * 2048 * 2 + (size_t)8192 * 5632 * 2;
    u16* fc1b  = (u16*)(ws + base_end);                 // 184.5 MB
    u16* fc2b  = (u16*)(ws + base_end + WELEM * 2);     // 184.5 MB
    u16* projb = fc1b;  // alias: proj converted AFTER gemm1 consumed fc1b (stream-ordered)
    const size_t need = base_end + 2 * WELEM * 2;       // 495,190,016 B

    hipMemsetAsync(cnt, 0, 8 * sizeof(int), stream);
    hipMemsetAsync(out, 0, (size_t)out_size * sizeof(float), stream);

    router_kernel<<<NTOK / 4, 256, 0, stream>>>(x, gate_w, cnt, tk_e, tk_p, tk_pos);
    scan_kernel<<<1, 64, 0, stream>>>(cnt, off);
    gather_kernel<<<NTOK * 2, 256, 0, stream>>>(x, tk_e, tk_p, tk_pos, off,
                                                slot_tok, slot_prob, Axg);

    if (ws_size >= need) {
        // bf16-weight fast path: pre-convert, then pure global_load_lds GEMMs
        cvt_bf16_kernel<<<2048, 256, 0, stream>>>(fc1_w, fc1b, (long long)(WELEM / 8));
        cvt_bf16_kernel<<<2048, 256, 0, stream>>>(fc2_w, fc2b, (long long)(WELEM / 8));
        gemm1_bf16<<<dim3(32, IDIM / 64, EDIM), 256, 0, stream>>>(Axg, fc1b, fc2b,
                                                                  cnt, off, hbuf);
        cvt_bf16_kernel<<<2048, 256, 0, stream>>>(proj_w, projb, (long long)(WELEM / 8));
        gemm2_bf16<<<dim3(32, CDIM / 128, EDIM), 256, 0, stream>>>(hbuf, projb, cnt, off,
                                                                   slot_tok, slot_prob, out);
    } else {
        // fallback: previous verified fp32-weight path
        gemm1_kernel<<<dim3(32, IDIM / 64, EDIM), 256, 0, stream>>>(Axg, fc1_w, fc2_w,
                                                                    cnt, off, hbuf);
        gemm2_kernel<<<dim3(32, CDIM / 64, EDIM), 256, 0, stream>>>(hbuf, proj_w, cnt, off,
                                                                    slot_tok, slot_prob, out);
    }
}